// Round 1
// baseline (747.566 us; speedup 1.0000x reference)
//
#include <hip/hip_runtime.h>

#define S_LEN   2048
#define HID     4096
#define NH      32
#define NKV     8
#define HD      128
#define QKV_N   (NH*HD + 2*NKV*HD)   // 6144
#define WINDOW  1024

typedef unsigned short u16;
typedef short s8v  __attribute__((ext_vector_type(8)));
typedef short s4v  __attribute__((ext_vector_type(4)));
typedef float f4v  __attribute__((ext_vector_type(4)));

#define MFMA16x32(a, b, c) __builtin_amdgcn_mfma_f32_16x16x32_bf16(a, b, c, 0, 0, 0)

typedef __attribute__((address_space(1))) const unsigned int g_u32;
typedef __attribute__((address_space(3))) unsigned int l_u32;

__device__ __forceinline__ float bf2f(u16 h) {
  union { unsigned int u; float f; } x;
  x.u = ((unsigned int)h) << 16;
  return x.f;
}
__device__ __forceinline__ u16 f2bf(float f) {
  union { float f; unsigned int u; } x;
  x.f = f;
  unsigned int u = x.u;
  return (u16)((u + 0x7FFFu + ((u >> 16) & 1u)) >> 16);
}

// ---------------------------------------------------------------------------
// f32 -> bf16 elementwise. n multiple of 1024. grid = n/1024, block 256.
// ---------------------------------------------------------------------------
__global__ __launch_bounds__(256) void cvt_bf16(const float* __restrict__ in,
                                               u16* __restrict__ out) {
  int i = (blockIdx.x * 256 + threadIdx.x) * 4;
  float4 v = *(const float4*)&in[i];
  u16 h[4] = { f2bf(v.x), f2bf(v.y), f2bf(v.z), f2bf(v.w) };
  *(s4v*)&out[i] = *(const s4v*)h;
}

// ---------------------------------------------------------------------------
// GEMM: C[M,N] = A[M,K](bf16) * B[N,K](bf16)^T + bias[N](f32)
// OUT_BF16: C bf16, else C f32. m97 structure: 128x128 tile, BK=32,
// global_load_lds width-16 staging, mfma 16x16x32 bf16.
// ---------------------------------------------------------------------------
template<int OUT_BF16>
__global__ __launch_bounds__(256) void gemm_bt(
    const u16* __restrict__ A, const u16* __restrict__ B,
    const float* __restrict__ bias, void* __restrict__ Cp,
    int M, int N, int K)
{
  __shared__ __align__(16) u16 sA[128 * 32];
  __shared__ __align__(16) u16 sB[128 * 32];
  const int tid  = threadIdx.x;
  const int lane = tid & 63;
  const int w    = tid >> 6;
  const int wr   = w >> 1, wc = w & 1;
  const int ln   = lane & 15, quad = lane >> 4;
  const long mBase = (long)blockIdx.y * 128;
  const long nBase = (long)blockIdx.x * 128;

  f4v acc[4][4];
#pragma unroll
  for (int i = 0; i < 4; ++i)
#pragma unroll
    for (int j = 0; j < 4; ++j)
#pragma unroll
      for (int r = 0; r < 4; ++r) acc[i][j][r] = 0.0f;

  const int steps = K >> 5;
  for (int kt = 0; kt < steps; ++kt) {
    __syncthreads();
#pragma unroll
    for (int p = 0; p < 2; ++p) {
      int c = p * 256 + tid;          // 16B chunk id
      int row = c >> 2, col = (c & 3) << 3;
      const u16* ga = A + (mBase + row) * (long)K + kt * 32 + col;
      const u16* gb = B + (nBase + row) * (long)K + kt * 32 + col;
      u16* la = sA + (p * 256 + w * 64) * 8;   // wave-uniform base
      u16* lb = sB + (p * 256 + w * 64) * 8;
      __builtin_amdgcn_global_load_lds((g_u32*)(const void*)ga, (l_u32*)(void*)la, 16, 0, 0);
      __builtin_amdgcn_global_load_lds((g_u32*)(const void*)gb, (l_u32*)(void*)lb, 16, 0, 0);
    }
    __syncthreads();

    s8v af[4], bfr[4];
#pragma unroll
    for (int i = 0; i < 4; ++i)
      af[i] = *(const s8v*)&sA[(wr * 64 + i * 16 + ln) * 32 + quad * 8];
#pragma unroll
    for (int j = 0; j < 4; ++j)
      bfr[j] = *(const s8v*)&sB[(wc * 64 + j * 16 + ln) * 32 + quad * 8];
#pragma unroll
    for (int i = 0; i < 4; ++i)
#pragma unroll
      for (int j = 0; j < 4; ++j)
        acc[i][j] = MFMA16x32(af[i], bfr[j], acc[i][j]);
  }

#pragma unroll
  for (int i = 0; i < 4; ++i) {
    long rowb = mBase + wr * 64 + i * 16 + quad * 4;
#pragma unroll
    for (int j = 0; j < 4; ++j) {
      long col = nBase + wc * 64 + j * 16 + ln;
      float bv = bias[col];
#pragma unroll
      for (int r = 0; r < 4; ++r) {
        float v = acc[i][j][r] + bv;
        if (OUT_BF16) ((u16*)Cp)[(rowb + r) * (long)N + col] = f2bf(v);
        else          ((float*)Cp)[(rowb + r) * (long)N + col] = v;
      }
    }
  }
}

// ---------------------------------------------------------------------------
// RoPE (YaRN, NEOX) on bf16 qkv; SCALE folded into q. One block per position.
// ---------------------------------------------------------------------------
__global__ __launch_bounds__(256) void rope_split(
    const u16* __restrict__ qkv, const int* __restrict__ positions,
    u16* __restrict__ qo, u16* __restrict__ ko, u16* __restrict__ vo)
{
  const int s = blockIdx.x;
  const int t = threadIdx.x;
  __shared__ float csh[64], snh[64];

  if (t < 64) {
    const double LN_BASE = log(500000.0);
    const double TWO_PI  = 6.283185307179586476925287;
    double cf  = 128.0 * log(32768.0 / (32.0 * TWO_PI)) / (2.0 * LN_BASE);
    double cs_ = 128.0 * log(32768.0 / TWO_PI) / (2.0 * LN_BASE);
    double lowd  = floor(cf);  if (lowd < 0.0)  lowd = 0.0;
    double highd = ceil(cs_);  if (highd > 63.0) highd = 63.0;
    double denom = highd - lowd; if (denom < 0.001) denom = 0.001;
    double d = (double)t;
    double inv_extra = exp(-LN_BASE * d / 64.0);
    double inv_inter = inv_extra * 0.25;
    double ramp = (d - lowd) / denom;
    ramp = ramp < 0.0 ? 0.0 : (ramp > 1.0 ? 1.0 : ramp);
    double maskv = 1.0 - ramp;
    double invf = inv_inter * (1.0 - maskv) + inv_extra * maskv;
    float freq = (float)positions[s] * (float)invf;
    const float msc = 1.1386294361119891f;
    csh[t] = cosf(freq) * msc;
    snh[t] = sinf(freq) * msc;
  }
  __syncthreads();

  const u16* row = qkv + (size_t)s * QKV_N;
  const float SC = 0.08838834764831845f;      // 128^-0.5

#pragma unroll
  for (int i = 0; i < 8; ++i) {
    int p = i * 256 + t;
    int hh = p >> 6, d = p & 63;
    float x1 = bf2f(row[hh * 128 + d]), x2 = bf2f(row[hh * 128 + d + 64]);
    float c = csh[d], sn = snh[d];
    qo[(size_t)s * 4096 + hh * 128 + d]      = f2bf((x1 * c - x2 * sn) * SC);
    qo[(size_t)s * 4096 + hh * 128 + d + 64] = f2bf((x2 * c + x1 * sn) * SC);
  }
#pragma unroll
  for (int i = 0; i < 2; ++i) {
    int p = i * 256 + t;
    int hh = p >> 6, d = p & 63;
    float x1 = bf2f(row[4096 + hh * 128 + d]), x2 = bf2f(row[4096 + hh * 128 + d + 64]);
    float c = csh[d], sn = snh[d];
    ko[(size_t)s * 1024 + hh * 128 + d]      = f2bf(x1 * c - x2 * sn);
    ko[(size_t)s * 1024 + hh * 128 + d + 64] = f2bf(x2 * c + x1 * sn);
  }
#pragma unroll
  for (int i = 0; i < 4; ++i) {
    int e = i * 256 + t;
    vo[(size_t)s * 1024 + e] = row[5120 + e];   // plain copy (already bf16)
  }
}

// ---------------------------------------------------------------------------
// V transpose: vb[2048][1024] -> vt[1024][2048] (u16). 64x64 tiles via LDS.
// grid (2048/64, 1024/64) = (32, 16), block 256.
// ---------------------------------------------------------------------------
__global__ __launch_bounds__(256) void transpose_v(const u16* __restrict__ vb,
                                                   u16* __restrict__ vt) {
  __shared__ u16 tile[64][72];
  const int s0 = blockIdx.x * 64, c0 = blockIdx.y * 64;
  const int tid = threadIdx.x;
#pragma unroll
  for (int t = 0; t < 2; ++t) {
    int row = t * 32 + (tid >> 3), col = (tid & 7) * 8;
    *(s8v*)&tile[row][col] = *(const s8v*)&vb[(size_t)(s0 + row) * 1024 + c0 + col];
  }
  __syncthreads();
#pragma unroll
  for (int t = 0; t < 2; ++t) {
    int orow = t * 32 + (tid >> 3), ocol = (tid & 7) * 8;
    u16 v[8];
#pragma unroll
    for (int e = 0; e < 8; ++e) v[e] = tile[ocol + e][orow];
    *(s8v*)&vt[(size_t)(c0 + orow) * 2048 + s0 + ocol] = *(const s8v*)v;
  }
}

// ---------------------------------------------------------------------------
// Flash attention v3: transposed scores D[key][q]. Grid (S/64, NH), 4 waves.
// CHANGE vs round 5: K and V^T fragments are read DIRECTLY from global
// (K/V per kv-head is 512 KB each -> L2/L3 resident; LDS staging was pure
// overhead, Common-mistake #7). This removes ALL __syncthreads from the
// k-loop: waves are fully independent. sP stays in a per-wave LDS slice;
// within-wave ds ordering enforced with s_waitcnt lgkmcnt(0)+sched_barrier
// (rule 18). LDS 45KB -> 26KB. s_setprio(1) wraps MFMA clusters (T5).
// Access pattern note: for each 16-row fragment read, quads 0..3 cover
// contiguous 64B per K/V row -> clean 64B segments; all 4 waves of the
// block read identical K/V bytes -> L1-served after first wave.
// ---------------------------------------------------------------------------
__global__ __launch_bounds__(256) void attn_fwd(
    const u16* __restrict__ Q, const u16* __restrict__ Kb,
    const u16* __restrict__ Vt, const float* __restrict__ sinks,
    u16* __restrict__ O)
{
  const int h = blockIdx.y, kvh = h >> 2;
  const int q0 = blockIdx.x * 64;
  const int tid = threadIdx.x, w = tid >> 6, lane = tid & 63;
  const int ln = lane & 15, quad = lane >> 4;
  const int qw = q0 + w * 16;        // wave's first query
  const int qi = qw + ln;            // this lane's query (n-index)

  __shared__ __align__(16) u16 sP[4][16 * 72];
  __shared__ __align__(16) u16 sO[64 * 136];

  // Q B-fragments: lane ln = q row; k = d (quad*8+j per 32-chunk)
  s8v qf[4];
  {
    const u16* qrow = Q + (size_t)qi * 4096 + h * 128;
#pragma unroll
    for (int kb = 0; kb < 4; ++kb)
      qf[kb] = *(const s8v*)&qrow[kb * 32 + quad * 8];
  }

  float m_v = sinks[h], l_v = 1.0f;
  f4v accO[8];
#pragma unroll
  for (int j = 0; j < 8; ++j)
#pragma unroll
    for (int r = 0; r < 4; ++r) accO[j][r] = 0.0f;

  int lo = q0 - (WINDOW - 1); if (lo < 0) lo = 0; lo &= ~63;

  // base pointers for direct-global fragment reads
  const u16* Kh = Kb + (size_t)kvh * 128 + quad * 8;          // + (s)*1024 + kb*32
  const u16* Vh = Vt + ((size_t)kvh * 128 + ln) * 2048 + quad * 8; // + (j*16)*2048 + kt + c2*32

  for (int kt = lo; kt <= q0; kt += 64) {
    // scores^T for 4 half-tiles of 16 keys: element (key=quad*4+r, q=ln)
    f4v sc[4];
    bool dead[4];
#pragma unroll
    for (int h4 = 0; h4 < 4; ++h4) {
      const int kb16 = kt + h4 * 16;
      dead[h4] = (kb16 > qw + 15) || (kb16 + 15 < qw - (WINDOW - 1));
      if (dead[h4]) {
#pragma unroll
        for (int r = 0; r < 4; ++r) sc[h4][r] = -1e30f;
        continue;
      }
      // K A-fragments straight from global (L1/L2-hot)
      const u16* krow = Kh + (size_t)(kb16 + ln) * 1024;
      s8v kf0 = *(const s8v*)&krow[0];
      s8v kf1 = *(const s8v*)&krow[32];
      s8v kf2 = *(const s8v*)&krow[64];
      s8v kf3 = *(const s8v*)&krow[96];
      f4v s;
#pragma unroll
      for (int r = 0; r < 4; ++r) s[r] = 0.0f;
      __builtin_amdgcn_s_setprio(1);
      s = MFMA16x32(kf0, qf[0], s);   // A=K rows (m=key), B=Q (n=q)
      s = MFMA16x32(kf1, qf[1], s);
      s = MFMA16x32(kf2, qf[2], s);
      s = MFMA16x32(kf3, qf[3], s);
      __builtin_amdgcn_s_setprio(0);
      const bool full = (kb16 + 15 <= qw) && (qw + 15 - kb16 <= WINDOW - 1);
      if (!full) {
        int base = qi - kb16 - quad * 4;   // qi - key for r=0
#pragma unroll
        for (int r = 0; r < 4; ++r)
          s[r] = ((unsigned)(base - r) <= (WINDOW - 1)) ? s[r] : -1e30f;
      }
      sc[h4] = s;
    }

    // online softmax: per-lane column q=ln; reduce 16 in-lane + 2 shfl
    float mn = m_v;
#pragma unroll
    for (int h4 = 0; h4 < 4; ++h4)
#pragma unroll
      for (int r = 0; r < 4; ++r) mn = fmaxf(mn, sc[h4][r]);
    mn = fmaxf(mn, __shfl_xor(mn, 16));
    mn = fmaxf(mn, __shfl_xor(mn, 32));

    float alpha = __expf(m_v - mn);
    m_v = mn;
    l_v *= alpha;
#pragma unroll
    for (int j = 0; j < 8; ++j)
#pragma unroll
      for (int r = 0; r < 4; ++r) accO[j][r] *= alpha;

    float lsum = 0.0f;
#pragma unroll
    for (int h4 = 0; h4 < 4; ++h4) {
      float p[4];
#pragma unroll
      for (int r = 0; r < 4; ++r) p[r] = __expf(sc[h4][r] - mn);
      lsum += (p[0] + p[1]) + (p[2] + p[3]);
      u16 pb[4] = { f2bf(p[0]), f2bf(p[1]), f2bf(p[2]), f2bf(p[3]) };
      *(s4v*)&sP[w][ln * 72 + h4 * 16 + quad * 4] = *(const s4v*)pb;
    }
    lsum += __shfl_xor(lsum, 16);
    lsum += __shfl_xor(lsum, 32);
    l_v += lsum;

    // within-wave sP visibility: drain DS writes, pin ordering (rule 18)
    asm volatile("s_waitcnt lgkmcnt(0)" ::: "memory");
    __builtin_amdgcn_sched_barrier(0);

    // PV: A = V^T rows (m=d, from global), B = P (n=q), k = 32-key chunks
#pragma unroll
    for (int c2 = 0; c2 < 2; ++c2) {
      if (dead[2 * c2] && dead[2 * c2 + 1]) continue;
      s8v pf = *(const s8v*)&sP[w][ln * 72 + c2 * 32 + quad * 8];
      const u16* vrow = Vh + kt + c2 * 32;
      __builtin_amdgcn_s_setprio(1);
#pragma unroll
      for (int j = 0; j < 8; ++j) {
        s8v vf = *(const s8v*)&vrow[(size_t)j * 16 * 2048];
        accO[j] = MFMA16x32(vf, pf, accO[j]);
      }
      __builtin_amdgcn_s_setprio(0);
    }
  }

  // epilogue: O^T (d rows, q cols) -> LDS transpose -> coalesced store.
  // sO slice is per-wave (rows w*16..w*16+15) -> within-wave ordering only.
  const float rl = 1.0f / l_v;
#pragma unroll
  for (int j = 0; j < 8; ++j) {
    u16 ob[4] = { f2bf(accO[j][0] * rl), f2bf(accO[j][1] * rl),
                  f2bf(accO[j][2] * rl), f2bf(accO[j][3] * rl) };
    *(s4v*)&sO[(w * 16 + ln) * 136 + j * 16 + quad * 4] = *(const s4v*)ob;
  }
  asm volatile("s_waitcnt lgkmcnt(0)" ::: "memory");
  __builtin_amdgcn_sched_barrier(0);
  {
    int row = lane >> 2, cc = lane & 3;
#pragma unroll
    for (int i = 0; i < 4; ++i) {
      s8v v = *(const s8v*)&sO[(w * 16 + row) * 136 + cc * 8 + i * 32];
      *(s8v*)&O[(size_t)(q0 + w * 16 + row) * 4096 + h * 128 + cc * 8 + i * 32] = v;
    }
  }
}

// ---------------------------------------------------------------------------
// Launch. Workspace peak = 92,274,688 B (round-2 proven footprint).
// Phase-aliased layout:
//   Region X [0, 48 MB):       qkv_w bf16 (dies after gemm1)
//                              -> qb@0 kb@16M vb@20M vt@24M attn@28M (45 MB)
//   Region Y [48 MB, 88 MB):   hidden bf16 @48M + qkvb @64M (dies after rope)
//                              -> o_w bf16 @48M (32 MB)
// ---------------------------------------------------------------------------
extern "C" void kernel_launch(void* const* d_in, const int* in_sizes, int n_in,
                              void* d_out, int out_size, void* d_ws, size_t ws_size,
                              hipStream_t stream) {
  const float* hidden    = (const float*)d_in[0];
  const int*   positions = (const int*)d_in[1];
  const float* qkv_w     = (const float*)d_in[2];
  const float* qkv_b     = (const float*)d_in[3];
  const float* o_w       = (const float*)d_in[4];
  const float* o_b       = (const float*)d_in[5];
  const float* sinks     = (const float*)d_in[6];

  char* ws = (char*)d_ws;
  // Region X
  u16* wW   = (u16*)ws;                         // 48 MB (phase A)
  u16* qb   = (u16*)ws;                         // 16 MB (phase B)
  u16* kb   = (u16*)(ws + 16777216ull);         //  4 MB
  u16* vb   = (u16*)(ws + 20971520ull);         //  4 MB
  u16* vt   = (u16*)(ws + 25165824ull);         //  4 MB
  u16* attn = (u16*)(ws + 29360128ull);         // 16 MB (ends 45 MB)
  // Region Y
  u16* hb   = (u16*)(ws + 50331648ull);         // 16 MB (phase A)
  u16* qkvb = (u16*)(ws + 67108864ull);         // 24 MB (ends 92,274,688)
  u16* oWb  = (u16*)(ws + 50331648ull);         // 32 MB (phase B, ends 84 MB)

  cvt_bf16<<<8192, 256, 0, stream>>>(hidden, hb);       // 2048*4096
  cvt_bf16<<<24576, 256, 0, stream>>>(qkv_w, wW);       // 6144*4096

  gemm_bt<1><<<dim3(QKV_N / 128, S_LEN / 128), 256, 0, stream>>>(
      hb, wW, qkv_b, (void*)qkvb, S_LEN, QKV_N, HID);   // wW, hb die here

  rope_split<<<S_LEN, 256, 0, stream>>>(qkvb, positions, qb, kb, vb); // qkvb dies

  cvt_bf16<<<16384, 256, 0, stream>>>(o_w, oWb);        // 4096*4096, region Y reuse

  transpose_v<<<dim3(32, 16), 256, 0, stream>>>(vb, vt);

  attn_fwd<<<dim3(S_LEN / 64, NH), 256, 0, stream>>>(qb, kb, vt, sinks, attn);

  gemm_bt<0><<<dim3(HID / 128, S_LEN / 128), 256, 0, stream>>>(
      attn, oWb, o_b, d_out, S_LEN, HID, HID);
}

// Round 2
// 525.214 us; speedup vs baseline: 1.4234x; 1.4234x over previous
//
#include <hip/hip_runtime.h>

#define S_LEN   2048
#define HID     4096
#define NH      32
#define NKV     8
#define HD      128
#define QKV_N   (NH*HD + 2*NKV*HD)   // 6144
#define WINDOW  1024

typedef unsigned short u16;
typedef short s8v  __attribute__((ext_vector_type(8)));
typedef short s4v  __attribute__((ext_vector_type(4)));
typedef float f4v  __attribute__((ext_vector_type(4)));

#define MFMA16x32(a, b, c) __builtin_amdgcn_mfma_f32_16x16x32_bf16(a, b, c, 0, 0, 0)

typedef __attribute__((address_space(1))) const unsigned int g_u32;
typedef __attribute__((address_space(3))) unsigned int l_u32;

__device__ __forceinline__ float bf2f(u16 h) {
  union { unsigned int u; float f; } x;
  x.u = ((unsigned int)h) << 16;
  return x.f;
}
__device__ __forceinline__ u16 f2bf(float f) {
  union { float f; unsigned int u; } x;
  x.f = f;
  unsigned int u = x.u;
  return (u16)((u + 0x7FFFu + ((u >> 16) & 1u)) >> 16);
}

// ---------------------------------------------------------------------------
// f32 -> bf16 elementwise. n multiple of 1024. grid = n/1024, block 256.
// ---------------------------------------------------------------------------
__global__ __launch_bounds__(256) void cvt_bf16(const float* __restrict__ in,
                                               u16* __restrict__ out) {
  int i = (blockIdx.x * 256 + threadIdx.x) * 4;
  float4 v = *(const float4*)&in[i];
  u16 h[4] = { f2bf(v.x), f2bf(v.y), f2bf(v.z), f2bf(v.w) };
  *(s4v*)&out[i] = *(const s4v*)h;
}

// ---------------------------------------------------------------------------
// GEMM v2: C[M,N] = A[M,K](bf16) * B[N,K](bf16)^T + bias[N](f32)
// Deep-pipelined big-tile structure (T2+T3+T4+T5):
//   BM=128, BN=256, BK=64; 512 threads = 8 waves (2M x 4N), 64x64 per wave.
//   3-deep LDS K-tile ring (3 x 48KB = 144KB): iteration t reads buf[t%3]
//   while staging tile t+2 into buf[(t+2)%3] via global_load_lds (6 x 8KB
//   issues/tile). Steady-state sync = s_waitcnt vmcnt(6) + s_barrier ONCE
//   per K-tile -- never drains to 0 in the main loop (T4).
//   LDS XOR swizzle (T2, rule-21 both-sides): linear LDS dest (gload_lds
//   requirement) + pre-swizzled GLOBAL source + same-swizzled ds_read addr.
//   swz(o) = o ^ ((o>>4)&0x60): XOR byte bits 5,6 with bits 9,10 (row bits
//   2,3 for 128B rows) -> 16-way ds_read_b128 conflict becomes 4-way.
//   2 phases per K-tile (ks=0,1): {8 ds_read_b128 || 3 gload_lds -> barrier
//   -> lgkmcnt(0) -> setprio(1) 16 MFMA setprio(0)}.
// Safety argument for counted vmcnt (per-wave counter): all waves issue
// stages in identical program order; vmcnt(6)+barrier => all but the 6
// newest loads (= tile t+2's, all waves) landed => tile t+1 fully resident.
// Buffer overwrite: stage of tile t+3 into buf[t%3] is issued after the
// end-of-t barrier, which every wave reaches only after its lgkmcnt(0)
// drained all its reads of buf[t%3].
// ---------------------------------------------------------------------------
template<int OUT_BF16>
__global__ __launch_bounds__(512, 2) void gemm_bt(
    const u16* __restrict__ A, const u16* __restrict__ B,
    const float* __restrict__ bias, void* __restrict__ Cp,
    int M, int N, int K)
{
  __shared__ __align__(16) char lds[3 * 49152];   // per buf: sA 16KB + sB 32KB
  const int tid  = threadIdx.x;
  const int lane = tid & 63;
  const int w    = tid >> 6;
  const int wm   = w >> 2, wn = w & 3;
  const int ln   = lane & 15, quad = lane >> 4;
  const long mBase = (long)blockIdx.y * 128;
  const long nBase = (long)blockIdx.x * 256;
  const u16* Ab = A + mBase * (long)K;
  const u16* Bb = B + nBase * (long)K;
  const long rs = (long)K * 2;                    // row stride bytes

  f4v acc[4][4];
#pragma unroll
  for (int i = 0; i < 4; ++i)
#pragma unroll
    for (int j = 0; j < 4; ++j)
#pragma unroll
      for (int r = 0; r < 4; ++r) acc[i][j][r] = 0.0f;

  const int nt = K >> 6;                          // K-tiles of 64

  // stage issues [i0,i1) of tile's 6: 0-1 = A half (64 rows each), 2-5 = B.
  auto stage = [&](int tile, int i0, int i1) {
    char* base = lds + (tile % 3) * 49152;
    const int ktb = tile * 128;                   // byte col of K-tile
#pragma unroll
    for (int k = i0; k < i1; ++k) {
      const u16* gsrc = (k < 2) ? Ab : Bb;
      char* ldst      = (k < 2) ? base : (base + 16384);
      const int kk    = (k < 2) ? k : (k - 2);
      int o  = kk * 8192 + w * 1024 + lane * 16;  // linear LDS byte offset
      int o2 = o ^ ((o >> 4) & 0x60);             // inverse-swizzled source pos
      const char* gp = (const char*)gsrc + (long)(o2 >> 7) * rs + ktb + (o2 & 127);
      __builtin_amdgcn_global_load_lds((g_u32*)(const void*)gp,
                                       (l_u32*)(void*)(ldst + kk * 8192 + w * 1024),
                                       16, 0, 0);
    }
  };

  // prologue: tiles 0 and 1 in flight; tile 0 resident before loop.
  stage(0, 0, 6);
  stage(1, 0, 6);
  asm volatile("s_waitcnt vmcnt(6)" ::: "memory");
  __builtin_amdgcn_sched_barrier(0);
  __builtin_amdgcn_s_barrier();

  int bsel = 0;
  for (int t = 0; t < nt; ++t) {
    char* base = lds + bsel * 49152;
    const bool doStage = (t + 2 < nt);

#pragma unroll
    for (int ks = 0; ks < 2; ++ks) {
      s8v af[4], bf[4];
#pragma unroll
      for (int f = 0; f < 4; ++f) {
        int r = wm * 64 + f * 16 + ln;
        int o = r * 128 + ks * 64 + quad * 16;
        o ^= (r & 12) << 3;                       // read-side swizzle
        af[f] = *(const s8v*)(base + o);
      }
#pragma unroll
      for (int j = 0; j < 4; ++j) {
        int r = wn * 64 + j * 16 + ln;
        int o = r * 128 + ks * 64 + quad * 16;
        o ^= (r & 12) << 3;
        bf[j] = *(const s8v*)(base + 16384 + o);
      }
      if (doStage) {
        if (ks == 0) stage(t + 2, 0, 3);
        else         stage(t + 2, 3, 6);
      }
      __builtin_amdgcn_s_barrier();               // all reads issued block-wide
      asm volatile("s_waitcnt lgkmcnt(0)" ::: "memory");
      __builtin_amdgcn_sched_barrier(0);          // rule 18: pin MFMA below
      __builtin_amdgcn_s_setprio(1);
#pragma unroll
      for (int i = 0; i < 4; ++i)
#pragma unroll
        for (int j = 0; j < 4; ++j)
          acc[i][j] = MFMA16x32(af[i], bf[j], acc[i][j]);
      __builtin_amdgcn_s_setprio(0);
    }

    // iteration-end sync: tile t+1 must be resident; tile t+2 stays in flight.
    if (t < nt - 2) {
      asm volatile("s_waitcnt vmcnt(6)" ::: "memory");
      __builtin_amdgcn_sched_barrier(0);
      __builtin_amdgcn_s_barrier();
    } else if (t == nt - 2) {
      asm volatile("s_waitcnt vmcnt(0)" ::: "memory");
      __builtin_amdgcn_sched_barrier(0);
      __builtin_amdgcn_s_barrier();
    }
    bsel = (bsel == 2) ? 0 : bsel + 1;
  }

#pragma unroll
  for (int i = 0; i < 4; ++i) {
    long rowb = mBase + wm * 64 + i * 16 + quad * 4;
#pragma unroll
    for (int j = 0; j < 4; ++j) {
      long col = nBase + wn * 64 + j * 16 + ln;
      float bv = bias[col];
#pragma unroll
      for (int r = 0; r < 4; ++r) {
        float v = acc[i][j][r] + bv;
        if (OUT_BF16) ((u16*)Cp)[(rowb + r) * (long)N + col] = f2bf(v);
        else          ((float*)Cp)[(rowb + r) * (long)N + col] = v;
      }
    }
  }
}

// ---------------------------------------------------------------------------
// RoPE (YaRN, NEOX) on bf16 qkv; SCALE folded into q. One block per position.
// ---------------------------------------------------------------------------
__global__ __launch_bounds__(256) void rope_split(
    const u16* __restrict__ qkv, const int* __restrict__ positions,
    u16* __restrict__ qo, u16* __restrict__ ko, u16* __restrict__ vo)
{
  const int s = blockIdx.x;
  const int t = threadIdx.x;
  __shared__ float csh[64], snh[64];

  if (t < 64) {
    const double LN_BASE = log(500000.0);
    const double TWO_PI  = 6.283185307179586476925287;
    double cf  = 128.0 * log(32768.0 / (32.0 * TWO_PI)) / (2.0 * LN_BASE);
    double cs_ = 128.0 * log(32768.0 / TWO_PI) / (2.0 * LN_BASE);
    double lowd  = floor(cf);  if (lowd < 0.0)  lowd = 0.0;
    double highd = ceil(cs_);  if (highd > 63.0) highd = 63.0;
    double denom = highd - lowd; if (denom < 0.001) denom = 0.001;
    double d = (double)t;
    double inv_extra = exp(-LN_BASE * d / 64.0);
    double inv_inter = inv_extra * 0.25;
    double ramp = (d - lowd) / denom;
    ramp = ramp < 0.0 ? 0.0 : (ramp > 1.0 ? 1.0 : ramp);
    double maskv = 1.0 - ramp;
    double invf = inv_inter * (1.0 - maskv) + inv_extra * maskv;
    float freq = (float)positions[s] * (float)invf;
    const float msc = 1.1386294361119891f;
    csh[t] = cosf(freq) * msc;
    snh[t] = sinf(freq) * msc;
  }
  __syncthreads();

  const u16* row = qkv + (size_t)s * QKV_N;
  const float SC = 0.08838834764831845f;      // 128^-0.5

#pragma unroll
  for (int i = 0; i < 8; ++i) {
    int p = i * 256 + t;
    int hh = p >> 6, d = p & 63;
    float x1 = bf2f(row[hh * 128 + d]), x2 = bf2f(row[hh * 128 + d + 64]);
    float c = csh[d], sn = snh[d];
    qo[(size_t)s * 4096 + hh * 128 + d]      = f2bf((x1 * c - x2 * sn) * SC);
    qo[(size_t)s * 4096 + hh * 128 + d + 64] = f2bf((x2 * c + x1 * sn) * SC);
  }
#pragma unroll
  for (int i = 0; i < 2; ++i) {
    int p = i * 256 + t;
    int hh = p >> 6, d = p & 63;
    float x1 = bf2f(row[4096 + hh * 128 + d]), x2 = bf2f(row[4096 + hh * 128 + d + 64]);
    float c = csh[d], sn = snh[d];
    ko[(size_t)s * 1024 + hh * 128 + d]      = f2bf(x1 * c - x2 * sn);
    ko[(size_t)s * 1024 + hh * 128 + d + 64] = f2bf(x2 * c + x1 * sn);
  }
#pragma unroll
  for (int i = 0; i < 4; ++i) {
    int e = i * 256 + t;
    vo[(size_t)s * 1024 + e] = row[5120 + e];   // plain copy (already bf16)
  }
}

// ---------------------------------------------------------------------------
// V transpose: vb[2048][1024] -> vt[1024][2048] (u16). 64x64 tiles via LDS.
// grid (2048/64, 1024/64) = (32, 16), block 256.
// ---------------------------------------------------------------------------
__global__ __launch_bounds__(256) void transpose_v(const u16* __restrict__ vb,
                                                   u16* __restrict__ vt) {
  __shared__ u16 tile[64][72];
  const int s0 = blockIdx.x * 64, c0 = blockIdx.y * 64;
  const int tid = threadIdx.x;
#pragma unroll
  for (int t = 0; t < 2; ++t) {
    int row = t * 32 + (tid >> 3), col = (tid & 7) * 8;
    *(s8v*)&tile[row][col] = *(const s8v*)&vb[(size_t)(s0 + row) * 1024 + c0 + col];
  }
  __syncthreads();
#pragma unroll
  for (int t = 0; t < 2; ++t) {
    int orow = t * 32 + (tid >> 3), ocol = (tid & 7) * 8;
    u16 v[8];
#pragma unroll
    for (int e = 0; e < 8; ++e) v[e] = tile[ocol + e][orow];
    *(s8v*)&vt[(size_t)(c0 + orow) * 2048 + s0 + ocol] = *(const s8v*)v;
  }
}

// ---------------------------------------------------------------------------
// Flash attention v2 (REVERTED to round-0 known-good): transposed scores
// D[key][q]. Grid (S/64, NH), 4 waves. Q in registers (B operand). K staged
// [64][136], V^T staged [128][72]. Softmax per-lane (q = ln) with 2 shuffles.
// ---------------------------------------------------------------------------
__global__ __launch_bounds__(256) void attn_fwd(
    const u16* __restrict__ Q, const u16* __restrict__ Kb,
    const u16* __restrict__ Vt, const float* __restrict__ sinks,
    u16* __restrict__ O)
{
  const int h = blockIdx.y, kvh = h >> 2;
  const int q0 = blockIdx.x * 64;
  const int tid = threadIdx.x, w = tid >> 6, lane = tid & 63;
  const int ln = lane & 15, quad = lane >> 4;
  const int qw = q0 + w * 16;        // wave's first query
  const int qi = qw + ln;            // this lane's query (n-index)

  __shared__ __align__(16) u16 sK[64 * 136];
  __shared__ __align__(16) u16 sVt[128 * 72];
  __shared__ __align__(16) u16 sP[4][16 * 72];

  // Q B-fragments: lane ln = q row; k = d (quad*8+j per 32-chunk)
  s8v qf[4];
  {
    const u16* qrow = Q + (size_t)qi * 4096 + h * 128;
#pragma unroll
    for (int kb = 0; kb < 4; ++kb)
      qf[kb] = *(const s8v*)&qrow[kb * 32 + quad * 8];
  }

  float m_v = sinks[h], l_v = 1.0f;
  f4v accO[8];
#pragma unroll
  for (int j = 0; j < 8; ++j)
#pragma unroll
    for (int r = 0; r < 4; ++r) accO[j][r] = 0.0f;

  int lo = q0 - (WINDOW - 1); if (lo < 0) lo = 0; lo &= ~63;

  for (int kt = lo; kt <= q0; kt += 64) {
    __syncthreads();
    // stage K tile: 64 keys x 128 dims, stride 136  (1024 chunks of 8 u16)
#pragma unroll
    for (int t = 0; t < 4; ++t) {
      int c = t * 256 + tid;
      int row = c >> 4, col = (c & 15) * 8;
      *(s8v*)&sK[row * 136 + col] =
          *(const s8v*)&Kb[(size_t)(kt + row) * 1024 + kvh * 128 + col];
    }
    // stage V^T tile: 128 dims x 64 keys, stride 72 (1024 chunks of 8 u16)
#pragma unroll
    for (int t = 0; t < 4; ++t) {
      int c = t * 256 + tid;
      int row = c >> 3, col = (c & 7) * 8;
      *(s8v*)&sVt[row * 72 + col] =
          *(const s8v*)&Vt[(size_t)(kvh * 128 + row) * 2048 + kt + col];
    }
    __syncthreads();

    // scores^T for 4 half-tiles of 16 keys: element (key=quad*4+r, q=ln)
    f4v sc[4];
    bool dead[4];
#pragma unroll
    for (int h4 = 0; h4 < 4; ++h4) {
      const int kb16 = kt + h4 * 16;
      dead[h4] = (kb16 > qw + 15) || (kb16 + 15 < qw - (WINDOW - 1));
      if (dead[h4]) {
#pragma unroll
        for (int r = 0; r < 4; ++r) sc[h4][r] = -1e30f;
        continue;
      }
      f4v s;
#pragma unroll
      for (int r = 0; r < 4; ++r) s[r] = 0.0f;
#pragma unroll
      for (int kb = 0; kb < 4; ++kb) {
        s8v kf = *(const s8v*)&sK[(h4 * 16 + ln) * 136 + kb * 32 + quad * 8];
        s = MFMA16x32(kf, qf[kb], s);   // A=K rows (m=key), B=Q (n=q)
      }
      const bool full = (kb16 + 15 <= qw) && (qw + 15 - kb16 <= WINDOW - 1);
      if (!full) {
        int base = qi - kb16 - quad * 4;   // qi - key for r=0
#pragma unroll
        for (int r = 0; r < 4; ++r)
          s[r] = ((unsigned)(base - r) <= (WINDOW - 1)) ? s[r] : -1e30f;
      }
      sc[h4] = s;
    }

    // online softmax: per-lane column q=ln; reduce 16 in-lane + 2 shfl
    float mn = m_v;
#pragma unroll
    for (int h4 = 0; h4 < 4; ++h4)
#pragma unroll
      for (int r = 0; r < 4; ++r) mn = fmaxf(mn, sc[h4][r]);
    mn = fmaxf(mn, __shfl_xor(mn, 16));
    mn = fmaxf(mn, __shfl_xor(mn, 32));

    float alpha = __expf(m_v - mn);
    m_v = mn;
    l_v *= alpha;
#pragma unroll
    for (int j = 0; j < 8; ++j)
#pragma unroll
      for (int r = 0; r < 4; ++r) accO[j][r] *= alpha;

    float lsum = 0.0f;
#pragma unroll
    for (int h4 = 0; h4 < 4; ++h4) {
      float p[4];
#pragma unroll
      for (int r = 0; r < 4; ++r) p[r] = __expf(sc[h4][r] - mn);
      lsum += (p[0] + p[1]) + (p[2] + p[3]);
      u16 pb[4] = { f2bf(p[0]), f2bf(p[1]), f2bf(p[2]), f2bf(p[3]) };
      *(s4v*)&sP[w][ln * 72 + h4 * 16 + quad * 4] = *(const s4v*)pb;
    }
    lsum += __shfl_xor(lsum, 16);
    lsum += __shfl_xor(lsum, 32);
    l_v += lsum;

    __syncthreads();   // cross-lane sP visibility (compiler ordering)

    // PV: A = V^T rows (m=d), B = P (n=q), k = 32-key chunks
#pragma unroll
    for (int c2 = 0; c2 < 2; ++c2) {
      if (dead[2 * c2] && dead[2 * c2 + 1]) continue;
      s8v pf = *(const s8v*)&sP[w][ln * 72 + c2 * 32 + quad * 8];
#pragma unroll
      for (int j = 0; j < 8; ++j) {
        s8v vf = *(const s8v*)&sVt[(j * 16 + ln) * 72 + c2 * 32 + quad * 8];
        accO[j] = MFMA16x32(vf, pf, accO[j]);
      }
    }
  }

  // epilogue: O^T (d rows, q cols) -> LDS transpose -> coalesced store
  __syncthreads();                    // all waves done with sK/sVt
  u16* sO = sK;                       // reuse: [64 q-rows][136]
  const float rl = 1.0f / l_v;
#pragma unroll
  for (int j = 0; j < 8; ++j) {
    u16 ob[4] = { f2bf(accO[j][0] * rl), f2bf(accO[j][1] * rl),
                  f2bf(accO[j][2] * rl), f2bf(accO[j][3] * rl) };
    *(s4v*)&sO[(w * 16 + ln) * 136 + j * 16 + quad * 4] = *(const s4v*)ob;
  }
  __syncthreads();                    // cross-lane sO visibility
  {
    int row = lane >> 2, cc = lane & 3;
#pragma unroll
    for (int i = 0; i < 4; ++i) {
      s8v v = *(const s8v*)&sO[(w * 16 + row) * 136 + cc * 8 + i * 32];
      *(s8v*)&O[(size_t)(q0 + w * 16 + row) * 4096 + h * 128 + cc * 8 + i * 32] = v;
    }
  }
}

// ---------------------------------------------------------------------------
// Launch. Workspace peak = 92,274,688 B (round-2 proven footprint).
// Phase-aliased layout:
//   Region X [0, 48 MB):       qkv_w bf16 (dies after gemm1)
//                              -> qb@0 kb@16M vb@20M vt@24M attn@28M (45 MB)
//   Region Y [48 MB, 88 MB):   hidden bf16 @48M + qkvb @64M (dies after rope)
//                              -> o_w bf16 @48M (32 MB)
// ---------------------------------------------------------------------------
extern "C" void kernel_launch(void* const* d_in, const int* in_sizes, int n_in,
                              void* d_out, int out_size, void* d_ws, size_t ws_size,
                              hipStream_t stream) {
  const float* hidden    = (const float*)d_in[0];
  const int*   positions = (const int*)d_in[1];
  const float* qkv_w     = (const float*)d_in[2];
  const float* qkv_b     = (const float*)d_in[3];
  const float* o_w       = (const float*)d_in[4];
  const float* o_b       = (const float*)d_in[5];
  const float* sinks     = (const float*)d_in[6];

  char* ws = (char*)d_ws;
  // Region X
  u16* wW   = (u16*)ws;                         // 48 MB (phase A)
  u16* qb   = (u16*)ws;                         // 16 MB (phase B)
  u16* kb   = (u16*)(ws + 16777216ull);         //  4 MB
  u16* vb   = (u16*)(ws + 20971520ull);         //  4 MB
  u16* vt   = (u16*)(ws + 25165824ull);         //  4 MB
  u16* attn = (u16*)(ws + 29360128ull);         // 16 MB (ends 45 MB)
  // Region Y
  u16* hb   = (u16*)(ws + 50331648ull);         // 16 MB (phase A)
  u16* qkvb = (u16*)(ws + 67108864ull);         // 24 MB (ends 92,274,688)
  u16* oWb  = (u16*)(ws + 50331648ull);         // 32 MB (phase B, ends 84 MB)

  cvt_bf16<<<8192, 256, 0, stream>>>(hidden, hb);       // 2048*4096
  cvt_bf16<<<24576, 256, 0, stream>>>(qkv_w, wW);       // 6144*4096

  gemm_bt<1><<<dim3(QKV_N / 256, S_LEN / 128), 512, 0, stream>>>(
      hb, wW, qkv_b, (void*)qkvb, S_LEN, QKV_N, HID);   // wW, hb die here

  rope_split<<<S_LEN, 256, 0, stream>>>(qkvb, positions, qb, kb, vb); // qkvb dies

  cvt_bf16<<<16384, 256, 0, stream>>>(o_w, oWb);        // 4096*4096, region Y reuse

  transpose_v<<<dim3(32, 16), 256, 0, stream>>>(vb, vt);

  attn_fwd<<<dim3(S_LEN / 64, NH), 256, 0, stream>>>(qb, kb, vt, sinks, attn);

  gemm_bt<0><<<dim3(HID / 256, S_LEN / 128), 512, 0, stream>>>(
      attn, oWb, o_b, d_out, S_LEN, HID, HID);
}

// Round 3
// 517.130 us; speedup vs baseline: 1.4456x; 1.0156x over previous
//
#include <hip/hip_runtime.h>

#define S_LEN   2048
#define HID     4096
#define NH      32
#define NKV     8
#define HD      128
#define QKV_N   (NH*HD + 2*NKV*HD)   // 6144
#define WINDOW  1024

typedef unsigned short u16;
typedef short s8v  __attribute__((ext_vector_type(8)));
typedef short s4v  __attribute__((ext_vector_type(4)));
typedef float f4v  __attribute__((ext_vector_type(4)));

#define MFMA16x32(a, b, c) __builtin_amdgcn_mfma_f32_16x16x32_bf16(a, b, c, 0, 0, 0)

typedef __attribute__((address_space(1))) const unsigned int g_u32;
typedef __attribute__((address_space(3))) unsigned int l_u32;

__device__ __forceinline__ float bf2f(u16 h) {
  union { unsigned int u; float f; } x;
  x.u = ((unsigned int)h) << 16;
  return x.f;
}
__device__ __forceinline__ u16 f2bf(float f) {
  union { float f; unsigned int u; } x;
  x.f = f;
  unsigned int u = x.u;
  return (u16)((u + 0x7FFFu + ((u >> 16) & 1u)) >> 16);
}

// ---------------------------------------------------------------------------
// f32 -> bf16 elementwise. n multiple of 1024. grid = n/1024, block 256.
// ---------------------------------------------------------------------------
__global__ __launch_bounds__(256) void cvt_bf16(const float* __restrict__ in,
                                               u16* __restrict__ out) {
  int i = (blockIdx.x * 256 + threadIdx.x) * 4;
  float4 v = *(const float4*)&in[i];
  u16 h[4] = { f2bf(v.x), f2bf(v.y), f2bf(v.z), f2bf(v.w) };
  *(s4v*)&out[i] = *(const s4v*)h;
}

// ---------------------------------------------------------------------------
// GEMM v3: C[M,N] = A[M,K](bf16) * B[N,K](bf16)^T + bias[N](f32)
//   BM=128, BN=256, BK=64; 512 threads = 8 waves (2M x 4N), 64x64 per wave.
//   3-deep LDS K-tile ring; steady sync = ONE {vmcnt(6); s_barrier} per
//   K-tile (T4 counted, never 0 mid-loop).
// CHANGES vs round 2 (m141 lesson — the per-phase pins WERE the stall):
//   (a) no per-phase barriers / lgkmcnt(0) / sched_barrier in the body —
//       reads are plain loads; compiler emits fine-grained lgkmcnt and
//       interleaves ds_read under MFMA itself. Hazard-free because reads
//       hit buf[t] while stages write buf[t+2]; the end-of-tile barrier
//       (after each wave's MFMAs consumed its reads) protects buf reuse.
//   (b) full 3-bit XOR swizzle o ^= ((o>>3)&0x70): granule bits 4-6 XOR
//       row bits 0-2 (involution; row bits untouched). Round-2's 2-bit
//       version left a 4-way conflict (SQ_LDS_BANK_CONFLICT unchanged);
//       3-bit spreads a wave64 b128 read uniformly over all 32 banks.
// vmcnt safety: per-wave counter; at end of tile t outstanding <= t+1's 6
// + t+2's 6; vmcnt(6) => own t+1 loads landed; barrier => ALL waves' t+1
// loads landed. Stage of t+3 into buf[t%3] only after that barrier.
// ---------------------------------------------------------------------------
template<int OUT_BF16>
__global__ __launch_bounds__(512, 2) void gemm_bt(
    const u16* __restrict__ A, const u16* __restrict__ B,
    const float* __restrict__ bias, void* __restrict__ Cp,
    int M, int N, int K)
{
  __shared__ __align__(16) char lds[3 * 49152];   // per buf: sA 16KB + sB 32KB
  const int tid  = threadIdx.x;
  const int lane = tid & 63;
  const int w    = tid >> 6;
  const int wm   = w >> 2, wn = w & 3;
  const int ln   = lane & 15, quad = lane >> 4;
  const long mBase = (long)blockIdx.y * 128;
  const long nBase = (long)blockIdx.x * 256;
  const u16* Ab = A + mBase * (long)K;
  const u16* Bb = B + nBase * (long)K;
  const long rs = (long)K * 2;                    // row stride bytes

  f4v acc[4][4];
#pragma unroll
  for (int i = 0; i < 4; ++i)
#pragma unroll
    for (int j = 0; j < 4; ++j)
#pragma unroll
      for (int r = 0; r < 4; ++r) acc[i][j][r] = 0.0f;

  const int nt = K >> 6;                          // K-tiles of 64

  // stage tile: 6 gload_lds per wave (0-1 = A 64-row halves, 2-5 = B).
  // LDS dest linear; global source inverse-swizzled (rule 21 both-sides).
  auto stage = [&](int tile) {
    char* base = lds + (tile % 3) * 49152;
    const int ktb = tile * 128;                   // byte col of K-tile
#pragma unroll
    for (int k = 0; k < 6; ++k) {
      const u16* gsrc = (k < 2) ? Ab : Bb;
      char* ldst      = (k < 2) ? base : (base + 16384);
      const int kk    = (k < 2) ? k : (k - 2);
      int o  = kk * 8192 + w * 1024 + lane * 16;  // linear LDS byte offset
      int o2 = o ^ ((o >> 3) & 0x70);             // inverse-swizzled source pos
      const char* gp = (const char*)gsrc + (long)(o2 >> 7) * rs + ktb + (o2 & 127);
      __builtin_amdgcn_global_load_lds((g_u32*)(const void*)gp,
                                       (l_u32*)(void*)(ldst + kk * 8192 + w * 1024),
                                       16, 0, 0);
    }
  };

  // prologue: tiles 0 and 1 in flight; tile 0 resident before loop.
  stage(0);
  stage(1);
  asm volatile("s_waitcnt vmcnt(6)" ::: "memory");
  __builtin_amdgcn_s_barrier();
  __builtin_amdgcn_sched_barrier(0);

  int bsel = 0;
  for (int t = 0; t < nt; ++t) {
    char* base = lds + bsel * 49152;
    if (t + 2 < nt) stage(t + 2);

    __builtin_amdgcn_s_setprio(1);
#pragma unroll
    for (int ks = 0; ks < 2; ++ks) {
      s8v af[4], bf[4];
#pragma unroll
      for (int f = 0; f < 4; ++f) {
        int r = wm * 64 + f * 16 + ln;
        int o = r * 128 + ks * 64 + quad * 16;
        o ^= (r & 7) << 4;                        // read-side swizzle
        af[f] = *(const s8v*)(base + o);
      }
#pragma unroll
      for (int j = 0; j < 4; ++j) {
        int r = wn * 64 + j * 16 + ln;
        int o = r * 128 + ks * 64 + quad * 16;
        o ^= (r & 7) << 4;
        bf[j] = *(const s8v*)(base + 16384 + o);
      }
#pragma unroll
      for (int i = 0; i < 4; ++i)
#pragma unroll
        for (int j = 0; j < 4; ++j)
          acc[i][j] = MFMA16x32(af[i], bf[j], acc[i][j]);
    }
    __builtin_amdgcn_s_setprio(0);

    // iteration-end sync: tile t+1 must be resident; tile t+2 stays in flight.
    if (t < nt - 2) {
      asm volatile("s_waitcnt vmcnt(6)" ::: "memory");
      __builtin_amdgcn_s_barrier();
      __builtin_amdgcn_sched_barrier(0);
    } else if (t == nt - 2) {
      asm volatile("s_waitcnt vmcnt(0)" ::: "memory");
      __builtin_amdgcn_s_barrier();
      __builtin_amdgcn_sched_barrier(0);
    }
    bsel = (bsel == 2) ? 0 : bsel + 1;
  }

#pragma unroll
  for (int i = 0; i < 4; ++i) {
    long rowb = mBase + wm * 64 + i * 16 + quad * 4;
#pragma unroll
    for (int j = 0; j < 4; ++j) {
      long col = nBase + wn * 64 + j * 16 + ln;
      float bv = bias[col];
#pragma unroll
      for (int r = 0; r < 4; ++r) {
        float v = acc[i][j][r] + bv;
        if (OUT_BF16) ((u16*)Cp)[(rowb + r) * (long)N + col] = f2bf(v);
        else          ((float*)Cp)[(rowb + r) * (long)N + col] = v;
      }
    }
  }
}

// ---------------------------------------------------------------------------
// RoPE (YaRN, NEOX) on bf16 qkv; SCALE folded into q. One block per position.
// ---------------------------------------------------------------------------
__global__ __launch_bounds__(256) void rope_split(
    const u16* __restrict__ qkv, const int* __restrict__ positions,
    u16* __restrict__ qo, u16* __restrict__ ko, u16* __restrict__ vo)
{
  const int s = blockIdx.x;
  const int t = threadIdx.x;
  __shared__ float csh[64], snh[64];

  if (t < 64) {
    const double LN_BASE = log(500000.0);
    const double TWO_PI  = 6.283185307179586476925287;
    double cf  = 128.0 * log(32768.0 / (32.0 * TWO_PI)) / (2.0 * LN_BASE);
    double cs_ = 128.0 * log(32768.0 / TWO_PI) / (2.0 * LN_BASE);
    double lowd  = floor(cf);  if (lowd < 0.0)  lowd = 0.0;
    double highd = ceil(cs_);  if (highd > 63.0) highd = 63.0;
    double denom = highd - lowd; if (denom < 0.001) denom = 0.001;
    double d = (double)t;
    double inv_extra = exp(-LN_BASE * d / 64.0);
    double inv_inter = inv_extra * 0.25;
    double ramp = (d - lowd) / denom;
    ramp = ramp < 0.0 ? 0.0 : (ramp > 1.0 ? 1.0 : ramp);
    double maskv = 1.0 - ramp;
    double invf = inv_inter * (1.0 - maskv) + inv_extra * maskv;
    float freq = (float)positions[s] * (float)invf;
    const float msc = 1.1386294361119891f;
    csh[t] = cosf(freq) * msc;
    snh[t] = sinf(freq) * msc;
  }
  __syncthreads();

  const u16* row = qkv + (size_t)s * QKV_N;
  const float SC = 0.08838834764831845f;      // 128^-0.5

#pragma unroll
  for (int i = 0; i < 8; ++i) {
    int p = i * 256 + t;
    int hh = p >> 6, d = p & 63;
    float x1 = bf2f(row[hh * 128 + d]), x2 = bf2f(row[hh * 128 + d + 64]);
    float c = csh[d], sn = snh[d];
    qo[(size_t)s * 4096 + hh * 128 + d]      = f2bf((x1 * c - x2 * sn) * SC);
    qo[(size_t)s * 4096 + hh * 128 + d + 64] = f2bf((x2 * c + x1 * sn) * SC);
  }
#pragma unroll
  for (int i = 0; i < 2; ++i) {
    int p = i * 256 + t;
    int hh = p >> 6, d = p & 63;
    float x1 = bf2f(row[4096 + hh * 128 + d]), x2 = bf2f(row[4096 + hh * 128 + d + 64]);
    float c = csh[d], sn = snh[d];
    ko[(size_t)s * 1024 + hh * 128 + d]      = f2bf(x1 * c - x2 * sn);
    ko[(size_t)s * 1024 + hh * 128 + d + 64] = f2bf(x2 * c + x1 * sn);
  }
#pragma unroll
  for (int i = 0; i < 4; ++i) {
    int e = i * 256 + t;
    vo[(size_t)s * 1024 + e] = row[5120 + e];   // plain copy (already bf16)
  }
}

// ---------------------------------------------------------------------------
// V transpose: vb[2048][1024] -> vt[1024][2048] (u16). 64x64 tiles via LDS.
// grid (2048/64, 1024/64) = (32, 16), block 256.
// ---------------------------------------------------------------------------
__global__ __launch_bounds__(256) void transpose_v(const u16* __restrict__ vb,
                                                   u16* __restrict__ vt) {
  __shared__ u16 tile[64][72];
  const int s0 = blockIdx.x * 64, c0 = blockIdx.y * 64;
  const int tid = threadIdx.x;
#pragma unroll
  for (int t = 0; t < 2; ++t) {
    int row = t * 32 + (tid >> 3), col = (tid & 7) * 8;
    *(s8v*)&tile[row][col] = *(const s8v*)&vb[(size_t)(s0 + row) * 1024 + c0 + col];
  }
  __syncthreads();
#pragma unroll
  for (int t = 0; t < 2; ++t) {
    int orow = t * 32 + (tid >> 3), ocol = (tid & 7) * 8;
    u16 v[8];
#pragma unroll
    for (int e = 0; e < 8; ++e) v[e] = tile[ocol + e][orow];
    *(s8v*)&vt[(size_t)(c0 + orow) * 2048 + s0 + ocol] = *(const s8v*)v;
  }
}

// ---------------------------------------------------------------------------
// Flash attention v2 (round-0 known-good): transposed scores D[key][q].
// Grid (S/64, NH), 4 waves. Q in registers (B operand). K staged [64][136],
// V^T staged [128][72]. Softmax per-lane (q = ln) with 2 shuffles.
// ---------------------------------------------------------------------------
__global__ __launch_bounds__(256) void attn_fwd(
    const u16* __restrict__ Q, const u16* __restrict__ Kb,
    const u16* __restrict__ Vt, const float* __restrict__ sinks,
    u16* __restrict__ O)
{
  const int h = blockIdx.y, kvh = h >> 2;
  const int q0 = blockIdx.x * 64;
  const int tid = threadIdx.x, w = tid >> 6, lane = tid & 63;
  const int ln = lane & 15, quad = lane >> 4;
  const int qw = q0 + w * 16;        // wave's first query
  const int qi = qw + ln;            // this lane's query (n-index)

  __shared__ __align__(16) u16 sK[64 * 136];
  __shared__ __align__(16) u16 sVt[128 * 72];
  __shared__ __align__(16) u16 sP[4][16 * 72];

  // Q B-fragments: lane ln = q row; k = d (quad*8+j per 32-chunk)
  s8v qf[4];
  {
    const u16* qrow = Q + (size_t)qi * 4096 + h * 128;
#pragma unroll
    for (int kb = 0; kb < 4; ++kb)
      qf[kb] = *(const s8v*)&qrow[kb * 32 + quad * 8];
  }

  float m_v = sinks[h], l_v = 1.0f;
  f4v accO[8];
#pragma unroll
  for (int j = 0; j < 8; ++j)
#pragma unroll
    for (int r = 0; r < 4; ++r) accO[j][r] = 0.0f;

  int lo = q0 - (WINDOW - 1); if (lo < 0) lo = 0; lo &= ~63;

  for (int kt = lo; kt <= q0; kt += 64) {
    __syncthreads();
    // stage K tile: 64 keys x 128 dims, stride 136  (1024 chunks of 8 u16)
#pragma unroll
    for (int t = 0; t < 4; ++t) {
      int c = t * 256 + tid;
      int row = c >> 4, col = (c & 15) * 8;
      *(s8v*)&sK[row * 136 + col] =
          *(const s8v*)&Kb[(size_t)(kt + row) * 1024 + kvh * 128 + col];
    }
    // stage V^T tile: 128 dims x 64 keys, stride 72 (1024 chunks of 8 u16)
#pragma unroll
    for (int t = 0; t < 4; ++t) {
      int c = t * 256 + tid;
      int row = c >> 3, col = (c & 7) * 8;
      *(s8v*)&sVt[row * 72 + col] =
          *(const s8v*)&Vt[(size_t)(kvh * 128 + row) * 2048 + kt + col];
    }
    __syncthreads();

    // scores^T for 4 half-tiles of 16 keys: element (key=quad*4+r, q=ln)
    f4v sc[4];
    bool dead[4];
#pragma unroll
    for (int h4 = 0; h4 < 4; ++h4) {
      const int kb16 = kt + h4 * 16;
      dead[h4] = (kb16 > qw + 15) || (kb16 + 15 < qw - (WINDOW - 1));
      if (dead[h4]) {
#pragma unroll
        for (int r = 0; r < 4; ++r) sc[h4][r] = -1e30f;
        continue;
      }
      f4v s;
#pragma unroll
      for (int r = 0; r < 4; ++r) s[r] = 0.0f;
#pragma unroll
      for (int kb = 0; kb < 4; ++kb) {
        s8v kf = *(const s8v*)&sK[(h4 * 16 + ln) * 136 + kb * 32 + quad * 8];
        s = MFMA16x32(kf, qf[kb], s);   // A=K rows (m=key), B=Q (n=q)
      }
      const bool full = (kb16 + 15 <= qw) && (qw + 15 - kb16 <= WINDOW - 1);
      if (!full) {
        int base = qi - kb16 - quad * 4;   // qi - key for r=0
#pragma unroll
        for (int r = 0; r < 4; ++r)
          s[r] = ((unsigned)(base - r) <= (WINDOW - 1)) ? s[r] : -1e30f;
      }
      sc[h4] = s;
    }

    // online softmax: per-lane column q=ln; reduce 16 in-lane + 2 shfl
    float mn = m_v;
#pragma unroll
    for (int h4 = 0; h4 < 4; ++h4)
#pragma unroll
      for (int r = 0; r < 4; ++r) mn = fmaxf(mn, sc[h4][r]);
    mn = fmaxf(mn, __shfl_xor(mn, 16));
    mn = fmaxf(mn, __shfl_xor(mn, 32));

    float alpha = __expf(m_v - mn);
    m_v = mn;
    l_v *= alpha;
#pragma unroll
    for (int j = 0; j < 8; ++j)
#pragma unroll
      for (int r = 0; r < 4; ++r) accO[j][r] *= alpha;

    float lsum = 0.0f;
#pragma unroll
    for (int h4 = 0; h4 < 4; ++h4) {
      float p[4];
#pragma unroll
      for (int r = 0; r < 4; ++r) p[r] = __expf(sc[h4][r] - mn);
      lsum += (p[0] + p[1]) + (p[2] + p[3]);
      u16 pb[4] = { f2bf(p[0]), f2bf(p[1]), f2bf(p[2]), f2bf(p[3]) };
      *(s4v*)&sP[w][ln * 72 + h4 * 16 + quad * 4] = *(const s4v*)pb;
    }
    lsum += __shfl_xor(lsum, 16);
    lsum += __shfl_xor(lsum, 32);
    l_v += lsum;

    __syncthreads();   // cross-lane sP visibility (compiler ordering)

    // PV: A = V^T rows (m=d), B = P (n=q), k = 32-key chunks
#pragma unroll
    for (int c2 = 0; c2 < 2; ++c2) {
      if (dead[2 * c2] && dead[2 * c2 + 1]) continue;
      s8v pf = *(const s8v*)&sP[w][ln * 72 + c2 * 32 + quad * 8];
#pragma unroll
      for (int j = 0; j < 8; ++j) {
        s8v vf = *(const s8v*)&sVt[(j * 16 + ln) * 72 + c2 * 32 + quad * 8];
        accO[j] = MFMA16x32(vf, pf, accO[j]);
      }
    }
  }

  // epilogue: O^T (d rows, q cols) -> LDS transpose -> coalesced store
  __syncthreads();                    // all waves done with sK/sVt
  u16* sO = sK;                       // reuse: [64 q-rows][136]
  const float rl = 1.0f / l_v;
#pragma unroll
  for (int j = 0; j < 8; ++j) {
    u16 ob[4] = { f2bf(accO[j][0] * rl), f2bf(accO[j][1] * rl),
                  f2bf(accO[j][2] * rl), f2bf(accO[j][3] * rl) };
    *(s4v*)&sO[(w * 16 + ln) * 136 + j * 16 + quad * 4] = *(const s4v*)ob;
  }
  __syncthreads();                    // cross-lane sO visibility
  {
    int row = lane >> 2, cc = lane & 3;
#pragma unroll
    for (int i = 0; i < 4; ++i) {
      s8v v = *(const s8v*)&sO[(w * 16 + row) * 136 + cc * 8 + i * 32];
      *(s8v*)&O[(size_t)(q0 + w * 16 + row) * 4096 + h * 128 + cc * 8 + i * 32] = v;
    }
  }
}

// ---------------------------------------------------------------------------
// Launch. Workspace peak = 92,274,688 B (round-2 proven footprint).
// Phase-aliased layout:
//   Region X [0, 48 MB):       qkv_w bf16 (dies after gemm1)
//                              -> qb@0 kb@16M vb@20M vt@24M attn@28M (45 MB)
//   Region Y [48 MB, 88 MB):   hidden bf16 @48M + qkvb @64M (dies after rope)
//                              -> o_w bf16 @48M (32 MB)
// ---------------------------------------------------------------------------
extern "C" void kernel_launch(void* const* d_in, const int* in_sizes, int n_in,
                              void* d_out, int out_size, void* d_ws, size_t ws_size,
                              hipStream_t stream) {
  const float* hidden    = (const float*)d_in[0];
  const int*   positions = (const int*)d_in[1];
  const float* qkv_w     = (const float*)d_in[2];
  const float* qkv_b     = (const float*)d_in[3];
  const float* o_w       = (const float*)d_in[4];
  const float* o_b       = (const float*)d_in[5];
  const float* sinks     = (const float*)d_in[6];

  char* ws = (char*)d_ws;
  // Region X
  u16* wW   = (u16*)ws;                         // 48 MB (phase A)
  u16* qb   = (u16*)ws;                         // 16 MB (phase B)
  u16* kb   = (u16*)(ws + 16777216ull);         //  4 MB
  u16* vb   = (u16*)(ws + 20971520ull);         //  4 MB
  u16* vt   = (u16*)(ws + 25165824ull);         //  4 MB
  u16* attn = (u16*)(ws + 29360128ull);         // 16 MB (ends 45 MB)
  // Region Y
  u16* hb   = (u16*)(ws + 50331648ull);         // 16 MB (phase A)
  u16* qkvb = (u16*)(ws + 67108864ull);         // 24 MB (ends 92,274,688)
  u16* oWb  = (u16*)(ws + 50331648ull);         // 32 MB (phase B, ends 84 MB)

  cvt_bf16<<<8192, 256, 0, stream>>>(hidden, hb);       // 2048*4096
  cvt_bf16<<<24576, 256, 0, stream>>>(qkv_w, wW);       // 6144*4096

  gemm_bt<1><<<dim3(QKV_N / 256, S_LEN / 128), 512, 0, stream>>>(
      hb, wW, qkv_b, (void*)qkvb, S_LEN, QKV_N, HID);   // wW, hb die here

  rope_split<<<S_LEN, 256, 0, stream>>>(qkvb, positions, qb, kb, vb); // qkvb dies

  cvt_bf16<<<16384, 256, 0, stream>>>(o_w, oWb);        // 4096*4096, region Y reuse

  transpose_v<<<dim3(32, 16), 256, 0, stream>>>(vb, vt);

  attn_fwd<<<dim3(S_LEN / 64, NH), 256, 0, stream>>>(qb, kb, vt, sinks, attn);

  gemm_bt<0><<<dim3(HID / 256, S_LEN / 128), 512, 0, stream>>>(
      attn, oWb, o_b, d_out, S_LEN, HID, HID);
}

// Round 4
// 511.743 us; speedup vs baseline: 1.4608x; 1.0105x over previous
//
#include <hip/hip_runtime.h>

#define S_LEN   2048
#define HID     4096
#define NH      32
#define NKV     8
#define HD      128
#define QKV_N   (NH*HD + 2*NKV*HD)   // 6144
#define WINDOW  1024

typedef unsigned short u16;
typedef short s8v  __attribute__((ext_vector_type(8)));
typedef short s4v  __attribute__((ext_vector_type(4)));
typedef float f4v  __attribute__((ext_vector_type(4)));

#define MFMA16x32(a, b, c) __builtin_amdgcn_mfma_f32_16x16x32_bf16(a, b, c, 0, 0, 0)

typedef __attribute__((address_space(1))) const unsigned int g_u32;
typedef __attribute__((address_space(3))) unsigned int l_u32;

__device__ __forceinline__ float bf2f(u16 h) {
  union { unsigned int u; float f; } x;
  x.u = ((unsigned int)h) << 16;
  return x.f;
}
__device__ __forceinline__ u16 f2bf(float f) {
  union { float f; unsigned int u; } x;
  x.f = f;
  unsigned int u = x.u;
  return (u16)((u + 0x7FFFu + ((u >> 16) & 1u)) >> 16);
}

// ---------------------------------------------------------------------------
// f32 -> bf16 elementwise. n multiple of 1024. grid = n/1024, block 256.
// ---------------------------------------------------------------------------
__global__ __launch_bounds__(256) void cvt_bf16(const float* __restrict__ in,
                                               u16* __restrict__ out) {
  int i = (blockIdx.x * 256 + threadIdx.x) * 4;
  float4 v = *(const float4*)&in[i];
  u16 h[4] = { f2bf(v.x), f2bf(v.y), f2bf(v.z), f2bf(v.w) };
  *(s4v*)&out[i] = *(const s4v*)h;
}

// ---------------------------------------------------------------------------
// Fused phase-A converts (one dispatch instead of two):
// blocks [0,24576): qkv_w -> wW;  [24576,32768): hidden -> hb.
// ---------------------------------------------------------------------------
__global__ __launch_bounds__(256) void cvt_fused(
    const float* __restrict__ hidden, const float* __restrict__ qkv_w,
    u16* __restrict__ hb, u16* __restrict__ wW) {
  int b = blockIdx.x;
  const float* in;
  u16* out;
  int i;
  if (b < 24576) { in = qkv_w;  out = wW; i = (b * 256 + threadIdx.x) * 4; }
  else           { in = hidden; out = hb; i = ((b - 24576) * 256 + threadIdx.x) * 4; }
  float4 v = *(const float4*)&in[i];
  u16 h[4] = { f2bf(v.x), f2bf(v.y), f2bf(v.z), f2bf(v.w) };
  *(s4v*)&out[i] = *(const s4v*)h;
}

// ---------------------------------------------------------------------------
// GEMM v4: C[M,N] = A[M,K](bf16) * B[N,K](bf16)^T + bias[N](f32)
//   BM=128, BN=256, BK=32; 512 threads = 8 waves (2M x 4N), 64x64 per wave.
// CHANGE vs round 3 (counters: conflicts=0 but MfmaUtil stuck at 30%;
// LDS-pipe model caps this geometry at ~45%; the 30->45 gap = per-tile
// sync lockstep that ONE block/CU cannot hide + 1.5-round grid tail):
//   BK 64->32 shrinks ring bufs to 24KB; 3-deep ring = 72KB LDS
//   -> TWO blocks/CU (16 waves/CU). Cross-block wave overlap (m114)
//   hides the per-tile vmcnt+barrier, and both grids (384, 256 blocks)
//   are now FULLY resident -> no tail rounds. __launch_bounds__(512,4)
//   pins VGPR <= 128 (acc 64 + frags 32 + addr; round-3 build was 88).
//   Counted vmcnt stays (T4): 3 loads/stage; steady wait = vmcnt(3).
//   Swizzle re-derived for 64B rows: o ^= ((o>>3)&0x30) (granule bits
//   4-5 XOR row bits 1-2; involution; 16-lane group covers 8 bank-slots
//   x 2 lanes = 2-way = free per m136).
// vmcnt safety: per-wave FIFO; at end of tile t outstanding = t+1's 3 +
// t+2's 3; vmcnt(3) => own t+1 landed; barrier => all waves' t+1 landed.
// Stage of t+3 into buf[t%3] only after that barrier.
// ---------------------------------------------------------------------------
template<int OUT_BF16>
__global__ __launch_bounds__(512, 4) void gemm_bt(
    const u16* __restrict__ A, const u16* __restrict__ B,
    const float* __restrict__ bias, void* __restrict__ Cp,
    int M, int N, int K)
{
  __shared__ __align__(16) char lds[3 * 24576];   // per buf: sA 8KB + sB 16KB
  const int tid  = threadIdx.x;
  const int lane = tid & 63;
  const int w    = tid >> 6;
  const int wm   = w >> 2, wn = w & 3;
  const int ln   = lane & 15, quad = lane >> 4;
  const long mBase = (long)blockIdx.y * 128;
  const long nBase = (long)blockIdx.x * 256;
  const u16* Ab = A + mBase * (long)K;
  const u16* Bb = B + nBase * (long)K;
  const long rs = (long)K * 2;                    // row stride bytes

  f4v acc[4][4];
#pragma unroll
  for (int i = 0; i < 4; ++i)
#pragma unroll
    for (int j = 0; j < 4; ++j)
#pragma unroll
      for (int r = 0; r < 4; ++r) acc[i][j][r] = 0.0f;

  const int nt = K >> 5;                          // K-tiles of 32

  // stage tile: 3 gload_lds per wave (0 = A, 1-2 = B halves).
  // LDS dest linear; global source inverse-swizzled (rule 21 both-sides).
  auto stage = [&](int tile) {
    char* base = lds + (tile % 3) * 24576;
    const int ktb = tile * 64;                    // byte col of K-tile
#pragma unroll
    for (int k = 0; k < 3; ++k) {
      const u16* gsrc = (k == 0) ? Ab : Bb;
      char* ldst      = (k == 0) ? base : (base + 8192);
      const int kk    = (k == 0) ? 0 : (k - 1);
      int o  = kk * 8192 + w * 1024 + lane * 16;  // linear region byte offset
      int o2 = o ^ ((o >> 3) & 0x30);             // inverse-swizzled source pos
      const char* gp = (const char*)gsrc + (long)(o2 >> 6) * rs + ktb + (o2 & 63);
      __builtin_amdgcn_global_load_lds((g_u32*)(const void*)gp,
                                       (l_u32*)(void*)(ldst + kk * 8192 + w * 1024),
                                       16, 0, 0);
    }
  };

  // prologue: tiles 0 and 1 in flight; tile 0 resident before loop.
  stage(0);
  stage(1);
  asm volatile("s_waitcnt vmcnt(3)" ::: "memory");
  __builtin_amdgcn_s_barrier();
  __builtin_amdgcn_sched_barrier(0);

  int bsel = 0;
  for (int t = 0; t < nt; ++t) {
    char* base = lds + bsel * 24576;
    if (t + 2 < nt) stage(t + 2);

    __builtin_amdgcn_s_setprio(1);
    s8v af[4], bf[4];
#pragma unroll
    for (int f = 0; f < 4; ++f) {
      int r = wm * 64 + f * 16 + ln;
      int o = r * 64 + quad * 16;
      o ^= (o >> 3) & 0x30;                       // read-side swizzle
      af[f] = *(const s8v*)(base + o);
    }
#pragma unroll
    for (int j = 0; j < 4; ++j) {
      int r = wn * 64 + j * 16 + ln;
      int o = r * 64 + quad * 16;
      o ^= (o >> 3) & 0x30;
      bf[j] = *(const s8v*)(base + 8192 + o);
    }
#pragma unroll
    for (int i = 0; i < 4; ++i)
#pragma unroll
      for (int j = 0; j < 4; ++j)
        acc[i][j] = MFMA16x32(af[i], bf[j], acc[i][j]);
    __builtin_amdgcn_s_setprio(0);

    // iteration-end sync: tile t+1 must be resident; tile t+2 stays in flight.
    if (t < nt - 2) {
      asm volatile("s_waitcnt vmcnt(3)" ::: "memory");
      __builtin_amdgcn_s_barrier();
      __builtin_amdgcn_sched_barrier(0);
    } else if (t == nt - 2) {
      asm volatile("s_waitcnt vmcnt(0)" ::: "memory");
      __builtin_amdgcn_s_barrier();
      __builtin_amdgcn_sched_barrier(0);
    }
    bsel = (bsel == 2) ? 0 : bsel + 1;
  }

#pragma unroll
  for (int i = 0; i < 4; ++i) {
    long rowb = mBase + wm * 64 + i * 16 + quad * 4;
#pragma unroll
    for (int j = 0; j < 4; ++j) {
      long col = nBase + wn * 64 + j * 16 + ln;
      float bv = bias[col];
#pragma unroll
      for (int r = 0; r < 4; ++r) {
        float v = acc[i][j][r] + bv;
        if (OUT_BF16) ((u16*)Cp)[(rowb + r) * (long)N + col] = f2bf(v);
        else          ((float*)Cp)[(rowb + r) * (long)N + col] = v;
      }
    }
  }
}

// ---------------------------------------------------------------------------
// RoPE (YaRN, NEOX) on bf16 qkv; SCALE folded into q. One block per position.
// ---------------------------------------------------------------------------
__global__ __launch_bounds__(256) void rope_split(
    const u16* __restrict__ qkv, const int* __restrict__ positions,
    u16* __restrict__ qo, u16* __restrict__ ko, u16* __restrict__ vo)
{
  const int s = blockIdx.x;
  const int t = threadIdx.x;
  __shared__ float csh[64], snh[64];

  if (t < 64) {
    const double LN_BASE = log(500000.0);
    const double TWO_PI  = 6.283185307179586476925287;
    double cf  = 128.0 * log(32768.0 / (32.0 * TWO_PI)) / (2.0 * LN_BASE);
    double cs_ = 128.0 * log(32768.0 / TWO_PI) / (2.0 * LN_BASE);
    double lowd  = floor(cf);  if (lowd < 0.0)  lowd = 0.0;
    double highd = ceil(cs_);  if (highd > 63.0) highd = 63.0;
    double denom = highd - lowd; if (denom < 0.001) denom = 0.001;
    double d = (double)t;
    double inv_extra = exp(-LN_BASE * d / 64.0);
    double inv_inter = inv_extra * 0.25;
    double ramp = (d - lowd) / denom;
    ramp = ramp < 0.0 ? 0.0 : (ramp > 1.0 ? 1.0 : ramp);
    double maskv = 1.0 - ramp;
    double invf = inv_inter * (1.0 - maskv) + inv_extra * maskv;
    float freq = (float)positions[s] * (float)invf;
    const float msc = 1.1386294361119891f;
    csh[t] = cosf(freq) * msc;
    snh[t] = sinf(freq) * msc;
  }
  __syncthreads();

  const u16* row = qkv + (size_t)s * QKV_N;
  const float SC = 0.08838834764831845f;      // 128^-0.5

#pragma unroll
  for (int i = 0; i < 8; ++i) {
    int p = i * 256 + t;
    int hh = p >> 6, d = p & 63;
    float x1 = bf2f(row[hh * 128 + d]), x2 = bf2f(row[hh * 128 + d + 64]);
    float c = csh[d], sn = snh[d];
    qo[(size_t)s * 4096 + hh * 128 + d]      = f2bf((x1 * c - x2 * sn) * SC);
    qo[(size_t)s * 4096 + hh * 128 + d + 64] = f2bf((x2 * c + x1 * sn) * SC);
  }
#pragma unroll
  for (int i = 0; i < 2; ++i) {
    int p = i * 256 + t;
    int hh = p >> 6, d = p & 63;
    float x1 = bf2f(row[4096 + hh * 128 + d]), x2 = bf2f(row[4096 + hh * 128 + d + 64]);
    float c = csh[d], sn = snh[d];
    ko[(size_t)s * 1024 + hh * 128 + d]      = f2bf(x1 * c - x2 * sn);
    ko[(size_t)s * 1024 + hh * 128 + d + 64] = f2bf(x2 * c + x1 * sn);
  }
#pragma unroll
  for (int i = 0; i < 4; ++i) {
    int e = i * 256 + t;
    vo[(size_t)s * 1024 + e] = row[5120 + e];   // plain copy (already bf16)
  }
}

// ---------------------------------------------------------------------------
// V transpose: vb[2048][1024] -> vt[1024][2048] (u16). 64x64 tiles via LDS.
// grid (2048/64, 1024/64) = (32, 16), block 256.
// ---------------------------------------------------------------------------
__global__ __launch_bounds__(256) void transpose_v(const u16* __restrict__ vb,
                                                   u16* __restrict__ vt) {
  __shared__ u16 tile[64][72];
  const int s0 = blockIdx.x * 64, c0 = blockIdx.y * 64;
  const int tid = threadIdx.x;
#pragma unroll
  for (int t = 0; t < 2; ++t) {
    int row = t * 32 + (tid >> 3), col = (tid & 7) * 8;
    *(s8v*)&tile[row][col] = *(const s8v*)&vb[(size_t)(s0 + row) * 1024 + c0 + col];
  }
  __syncthreads();
#pragma unroll
  for (int t = 0; t < 2; ++t) {
    int orow = t * 32 + (tid >> 3), ocol = (tid & 7) * 8;
    u16 v[8];
#pragma unroll
    for (int e = 0; e < 8; ++e) v[e] = tile[ocol + e][orow];
    *(s8v*)&vt[(size_t)(c0 + orow) * 2048 + s0 + ocol] = *(const s8v*)v;
  }
}

// ---------------------------------------------------------------------------
// Flash attention v2 (round-0 known-good): transposed scores D[key][q].
// Grid (S/64, NH), 4 waves. Q in registers (B operand). K staged [64][136],
// V^T staged [128][72]. Softmax per-lane (q = ln) with 2 shuffles.
// ---------------------------------------------------------------------------
__global__ __launch_bounds__(256) void attn_fwd(
    const u16* __restrict__ Q, const u16* __restrict__ Kb,
    const u16* __restrict__ Vt, const float* __restrict__ sinks,
    u16* __restrict__ O)
{
  const int h = blockIdx.y, kvh = h >> 2;
  const int q0 = blockIdx.x * 64;
  const int tid = threadIdx.x, w = tid >> 6, lane = tid & 63;
  const int ln = lane & 15, quad = lane >> 4;
  const int qw = q0 + w * 16;        // wave's first query
  const int qi = qw + ln;            // this lane's query (n-index)

  __shared__ __align__(16) u16 sK[64 * 136];
  __shared__ __align__(16) u16 sVt[128 * 72];
  __shared__ __align__(16) u16 sP[4][16 * 72];

  // Q B-fragments: lane ln = q row; k = d (quad*8+j per 32-chunk)
  s8v qf[4];
  {
    const u16* qrow = Q + (size_t)qi * 4096 + h * 128;
#pragma unroll
    for (int kb = 0; kb < 4; ++kb)
      qf[kb] = *(const s8v*)&qrow[kb * 32 + quad * 8];
  }

  float m_v = sinks[h], l_v = 1.0f;
  f4v accO[8];
#pragma unroll
  for (int j = 0; j < 8; ++j)
#pragma unroll
    for (int r = 0; r < 4; ++r) accO[j][r] = 0.0f;

  int lo = q0 - (WINDOW - 1); if (lo < 0) lo = 0; lo &= ~63;

  for (int kt = lo; kt <= q0; kt += 64) {
    __syncthreads();
    // stage K tile: 64 keys x 128 dims, stride 136  (1024 chunks of 8 u16)
#pragma unroll
    for (int t = 0; t < 4; ++t) {
      int c = t * 256 + tid;
      int row = c >> 4, col = (c & 15) * 8;
      *(s8v*)&sK[row * 136 + col] =
          *(const s8v*)&Kb[(size_t)(kt + row) * 1024 + kvh * 128 + col];
    }
    // stage V^T tile: 128 dims x 64 keys, stride 72 (1024 chunks of 8 u16)
#pragma unroll
    for (int t = 0; t < 4; ++t) {
      int c = t * 256 + tid;
      int row = c >> 3, col = (c & 7) * 8;
      *(s8v*)&sVt[row * 72 + col] =
          *(const s8v*)&Vt[(size_t)(kvh * 128 + row) * 2048 + kt + col];
    }
    __syncthreads();

    // scores^T for 4 half-tiles of 16 keys: element (key=quad*4+r, q=ln)
    f4v sc[4];
    bool dead[4];
#pragma unroll
    for (int h4 = 0; h4 < 4; ++h4) {
      const int kb16 = kt + h4 * 16;
      dead[h4] = (kb16 > qw + 15) || (kb16 + 15 < qw - (WINDOW - 1));
      if (dead[h4]) {
#pragma unroll
        for (int r = 0; r < 4; ++r) sc[h4][r] = -1e30f;
        continue;
      }
      f4v s;
#pragma unroll
      for (int r = 0; r < 4; ++r) s[r] = 0.0f;
#pragma unroll
      for (int kb = 0; kb < 4; ++kb) {
        s8v kf = *(const s8v*)&sK[(h4 * 16 + ln) * 136 + kb * 32 + quad * 8];
        s = MFMA16x32(kf, qf[kb], s);   // A=K rows (m=key), B=Q (n=q)
      }
      const bool full = (kb16 + 15 <= qw) && (qw + 15 - kb16 <= WINDOW - 1);
      if (!full) {
        int base = qi - kb16 - quad * 4;   // qi - key for r=0
#pragma unroll
        for (int r = 0; r < 4; ++r)
          s[r] = ((unsigned)(base - r) <= (WINDOW - 1)) ? s[r] : -1e30f;
      }
      sc[h4] = s;
    }

    // online softmax: per-lane column q=ln; reduce 16 in-lane + 2 shfl
    float mn = m_v;
#pragma unroll
    for (int h4 = 0; h4 < 4; ++h4)
#pragma unroll
      for (int r = 0; r < 4; ++r) mn = fmaxf(mn, sc[h4][r]);
    mn = fmaxf(mn, __shfl_xor(mn, 16));
    mn = fmaxf(mn, __shfl_xor(mn, 32));

    float alpha = __expf(m_v - mn);
    m_v = mn;
    l_v *= alpha;
#pragma unroll
    for (int j = 0; j < 8; ++j)
#pragma unroll
      for (int r = 0; r < 4; ++r) accO[j][r] *= alpha;

    float lsum = 0.0f;
#pragma unroll
    for (int h4 = 0; h4 < 4; ++h4) {
      float p[4];
#pragma unroll
      for (int r = 0; r < 4; ++r) p[r] = __expf(sc[h4][r] - mn);
      lsum += (p[0] + p[1]) + (p[2] + p[3]);
      u16 pb[4] = { f2bf(p[0]), f2bf(p[1]), f2bf(p[2]), f2bf(p[3]) };
      *(s4v*)&sP[w][ln * 72 + h4 * 16 + quad * 4] = *(const s4v*)pb;
    }
    lsum += __shfl_xor(lsum, 16);
    lsum += __shfl_xor(lsum, 32);
    l_v += lsum;

    __syncthreads();   // cross-lane sP visibility (compiler ordering)

    // PV: A = V^T rows (m=d), B = P (n=q), k = 32-key chunks
#pragma unroll
    for (int c2 = 0; c2 < 2; ++c2) {
      if (dead[2 * c2] && dead[2 * c2 + 1]) continue;
      s8v pf = *(const s8v*)&sP[w][ln * 72 + c2 * 32 + quad * 8];
#pragma unroll
      for (int j = 0; j < 8; ++j) {
        s8v vf = *(const s8v*)&sVt[(j * 16 + ln) * 72 + c2 * 32 + quad * 8];
        accO[j] = MFMA16x32(vf, pf, accO[j]);
      }
    }
  }

  // epilogue: O^T (d rows, q cols) -> LDS transpose -> coalesced store
  __syncthreads();                    // all waves done with sK/sVt
  u16* sO = sK;                       // reuse: [64 q-rows][136]
  const float rl = 1.0f / l_v;
#pragma unroll
  for (int j = 0; j < 8; ++j) {
    u16 ob[4] = { f2bf(accO[j][0] * rl), f2bf(accO[j][1] * rl),
                  f2bf(accO[j][2] * rl), f2bf(accO[j][3] * rl) };
    *(s4v*)&sO[(w * 16 + ln) * 136 + j * 16 + quad * 4] = *(const s4v*)ob;
  }
  __syncthreads();                    // cross-lane sO visibility
  {
    int row = lane >> 2, cc = lane & 3;
#pragma unroll
    for (int i = 0; i < 4; ++i) {
      s8v v = *(const s8v*)&sO[(w * 16 + row) * 136 + cc * 8 + i * 32];
      *(s8v*)&O[(size_t)(q0 + w * 16 + row) * 4096 + h * 128 + cc * 8 + i * 32] = v;
    }
  }
}

// ---------------------------------------------------------------------------
// Launch. Workspace peak = 92,274,688 B (round-2 proven footprint).
// Phase-aliased layout:
//   Region X [0, 48 MB):       qkv_w bf16 (dies after gemm1)
//                              -> qb@0 kb@16M vb@20M vt@24M attn@28M (45 MB)
//   Region Y [48 MB, 88 MB):   hidden bf16 @48M + qkvb @64M (dies after rope)
//                              -> o_w bf16 @48M (32 MB)
// ---------------------------------------------------------------------------
extern "C" void kernel_launch(void* const* d_in, const int* in_sizes, int n_in,
                              void* d_out, int out_size, void* d_ws, size_t ws_size,
                              hipStream_t stream) {
  const float* hidden    = (const float*)d_in[0];
  const int*   positions = (const int*)d_in[1];
  const float* qkv_w     = (const float*)d_in[2];
  const float* qkv_b     = (const float*)d_in[3];
  const float* o_w       = (const float*)d_in[4];
  const float* o_b       = (const float*)d_in[5];
  const float* sinks     = (const float*)d_in[6];

  char* ws = (char*)d_ws;
  // Region X
  u16* wW   = (u16*)ws;                         // 48 MB (phase A)
  u16* qb   = (u16*)ws;                         // 16 MB (phase B)
  u16* kb   = (u16*)(ws + 16777216ull);         //  4 MB
  u16* vb   = (u16*)(ws + 20971520ull);         //  4 MB
  u16* vt   = (u16*)(ws + 25165824ull);         //  4 MB
  u16* attn = (u16*)(ws + 29360128ull);         // 16 MB (ends 45 MB)
  // Region Y
  u16* hb   = (u16*)(ws + 50331648ull);         // 16 MB (phase A)
  u16* qkvb = (u16*)(ws + 67108864ull);         // 24 MB (ends 92,274,688)
  u16* oWb  = (u16*)(ws + 50331648ull);         // 32 MB (phase B, ends 84 MB)

  cvt_fused<<<32768, 256, 0, stream>>>(hidden, qkv_w, hb, wW);

  gemm_bt<1><<<dim3(QKV_N / 256, S_LEN / 128), 512, 0, stream>>>(
      hb, wW, qkv_b, (void*)qkvb, S_LEN, QKV_N, HID);   // wW, hb die here

  rope_split<<<S_LEN, 256, 0, stream>>>(qkvb, positions, qb, kb, vb); // qkvb dies

  cvt_bf16<<<16384, 256, 0, stream>>>(o_w, oWb);        // 4096*4096, region Y reuse

  transpose_v<<<dim3(32, 16), 256, 0, stream>>>(vb, vt);

  attn_fwd<<<dim3(S_LEN / 64, NH), 256, 0, stream>>>(qb, kb, vt, sinks, attn);

  gemm_bt<0><<<dim3(HID / 256, S_LEN / 128), 512, 0, stream>>>(
      attn, oWb, o_b, d_out, S_LEN, HID, HID);
}